// Round 1
// baseline (354.939 us; speedup 1.0000x reference)
//
#include <hip/hip_runtime.h>

// result = sum_i | sum_j flow[i,j] - sum_j flow[j,i] |, N=8192 fp32.
// R5: remove ALL accumulation atomics + the 32KB memset + the 1-block finale.
//   pass1: grid (32,128), block 256. Each block owns 64 rows x 64 float4 cols
//     (64 KB). Identical coalesced streaming as R4 (1 KB per wave-load), but
//     partials are written ONCE each, no atomics:
//       rowpart[bx][row]  : this block's 256-col contribution to row sums
//       colpart[by][col4] : this block's 64-row contribution to col sums (f4)
//   pass2: 8 blocks x 256 threads. Thread j (f4-col index) folds 128 colpart
//     rows + 32 rowpart rows (all float4, coalesced), computes sum|r-c|,
//     block-reduces, 8 atomicAdds into out[0] (zeroed by a 4-byte memset).
//   Extra HBM traffic vs R4: +5 MB write +5 MB read (~1.6 us) for the removal
//   of 1.31M device-scope atomics and the single-CU abs_reduce tail.

constexpr int N = 8192;
constexpr int N4 = N / 4;  // 2048 float4 per row

// ws layout:
//   [0, 4 MB)      : colpart, 128 * 2048 float4  (by-band column partials)
//   [4 MB, 5 MB)   : rowpart, 32 * 8192 float    (bx-band row partials)

__global__ __launch_bounds__(256) void pass1_kernel(
    const float* __restrict__ flow, float4* __restrict__ colpart,
    float* __restrict__ rowpart) {
  const int wave = threadIdx.x >> 6;
  const int lane = threadIdx.x & 63;
  const int c4 = blockIdx.x * 64 + lane;        // this thread's float4 column
  const int row0 = blockIdx.y * 64 + wave * 16; // 16 consecutive rows per wave

  __shared__ float rowbuf[64 * 65];   // 16.6 KB, +1 pad -> conflict-free
  __shared__ float4 colbuf[4 * 64];   // 4 KB

  const float4* __restrict__ flow4 = reinterpret_cast<const float4*>(flow);

  float4 ca = make_float4(0.f, 0.f, 0.f, 0.f);
#pragma unroll
  for (int i = 0; i < 16; ++i) {
    float4 v = flow4[(size_t)(row0 + i) * N4 + c4];  // 1 KB/wave, coalesced
    ca.x += v.x; ca.y += v.y; ca.z += v.z; ca.w += v.w;
    rowbuf[(wave * 16 + i) * 65 + lane] = (v.x + v.y) + (v.z + v.w);
  }
  colbuf[wave * 64 + lane] = ca;
  __syncthreads();

  if (threadIdx.x < 64) {
    // wave 0: row reduce. thread t sums 64 lane-partials of row t.
    // addresses t*65+l: banks (t+l)%32 distinct per half-wave -> conflict-free.
    float s = 0.f;
#pragma unroll 8
    for (int l = 0; l < 64; ++l) s += rowbuf[threadIdx.x * 65 + l];
    // write-once, no atomic: each (bx, row) cell has exactly one producer.
    rowpart[(size_t)blockIdx.x * N + blockIdx.y * 64 + threadIdx.x] = s;
  } else if (threadIdx.x < 128) {
    // wave 1 (concurrent with wave 0): column reduce over this block's 64 rows.
    const int l = threadIdx.x - 64;
    float4 a = colbuf[l], b = colbuf[64 + l], c = colbuf[128 + l],
           d = colbuf[192 + l];
    float4 s = make_float4((a.x + b.x) + (c.x + d.x),
                           (a.y + b.y) + (c.y + d.y),
                           (a.z + b.z) + (c.z + d.z),
                           (a.w + b.w) + (c.w + d.w));
    // write-once, no atomic: one float4 store instead of 4 contended atomics.
    colpart[(size_t)blockIdx.y * N4 + blockIdx.x * 64 + l] = s;
  }
}

__global__ __launch_bounds__(256) void pass2_kernel(
    const float4* __restrict__ colpart, const float* __restrict__ rowpart,
    float* __restrict__ out) {
  const int j = blockIdx.x * 256 + threadIdx.x;  // f4-col index, 0..2047

  float4 c = make_float4(0.f, 0.f, 0.f, 0.f);
#pragma unroll 8
  for (int by = 0; by < 128; ++by) {  // coalesced: stride N4 f4 across rows
    float4 v = colpart[(size_t)by * N4 + j];
    c.x += v.x; c.y += v.y; c.z += v.z; c.w += v.w;
  }

  const float4* __restrict__ rowpart4 =
      reinterpret_cast<const float4*>(rowpart);
  float4 r = make_float4(0.f, 0.f, 0.f, 0.f);
#pragma unroll
  for (int bx = 0; bx < 32; ++bx) {
    float4 v = rowpart4[(size_t)bx * N4 + j];
    r.x += v.x; r.y += v.y; r.z += v.z; r.w += v.w;
  }

  float s = (fabsf(r.x - c.x) + fabsf(r.y - c.y)) +
            (fabsf(r.z - c.z) + fabsf(r.w - c.w));
#pragma unroll
  for (int off = 32; off > 0; off >>= 1) s += __shfl_down(s, off, 64);

  __shared__ float wsum[4];
  if ((threadIdx.x & 63) == 0) wsum[threadIdx.x >> 6] = s;
  __syncthreads();
  if (threadIdx.x == 0)
    atomicAdd(out, (wsum[0] + wsum[1]) + (wsum[2] + wsum[3]));
}

extern "C" void kernel_launch(void* const* d_in, const int* in_sizes, int n_in,
                              void* d_out, int out_size, void* d_ws, size_t ws_size,
                              hipStream_t stream) {
  const float* flow = (const float*)d_in[0];
  float* out = (float*)d_out;
  float4* colpart = (float4*)d_ws;                       // 4 MB
  float* rowpart = (float*)((char*)d_ws + (size_t)4 * 1024 * 1024);  // 1 MB

  hipMemsetAsync(out, 0, sizeof(float), stream);  // 4 bytes, only init needed

  dim3 grid(N / 256, N / 64);  // (32, 128) = 4096 blocks
  pass1_kernel<<<grid, 256, 0, stream>>>(flow, colpart, rowpart);
  pass2_kernel<<<8, 256, 0, stream>>>(colpart, rowpart, out);
}

// Round 2
// 351.116 us; speedup vs baseline: 1.0109x; 1.0109x over previous
//
#include <hip/hip_runtime.h>

// result = sum_i | sum_j flow[i,j] - sum_j flow[j,i] |, N=8192 fp32.
// R6: R5 with a 4x-parallel pass2. Accounting from R4/R5: the timed window is
//   ~2 x 1-GiB harness poison fills (~300-320 us, at 83-85% HBM peak, not ours)
//   + pass1 (~45 us, compulsory 268 MB stream) + pass2 tail. R5's pass2 ran on
//   only 8 CUs folding 5 MB with long dependent load chains -> latency-bound.
//   R6 pass2: 32 blocks, 4 threads per f4-column (8192 threads), quarter-split
//   fold + __shfl_xor(1,2) combine. Pass1 unchanged (clean A/B on pass2 only).

constexpr int N = 8192;
constexpr int N4 = N / 4;  // 2048 float4 per row

// ws layout:
//   [0, 4 MB)      : colpart, 128 * 2048 float4  (by-band column partials)
//   [4 MB, 5 MB)   : rowpart, 32 * 8192 float    (bx-band row partials)

__global__ __launch_bounds__(256) void pass1_kernel(
    const float* __restrict__ flow, float4* __restrict__ colpart,
    float* __restrict__ rowpart) {
  const int wave = threadIdx.x >> 6;
  const int lane = threadIdx.x & 63;
  const int c4 = blockIdx.x * 64 + lane;        // this thread's float4 column
  const int row0 = blockIdx.y * 64 + wave * 16; // 16 consecutive rows per wave

  __shared__ float rowbuf[64 * 65];   // 16.6 KB, +1 pad -> conflict-free
  __shared__ float4 colbuf[4 * 64];   // 4 KB

  const float4* __restrict__ flow4 = reinterpret_cast<const float4*>(flow);

  float4 ca = make_float4(0.f, 0.f, 0.f, 0.f);
#pragma unroll
  for (int i = 0; i < 16; ++i) {
    float4 v = flow4[(size_t)(row0 + i) * N4 + c4];  // 1 KB/wave, coalesced
    ca.x += v.x; ca.y += v.y; ca.z += v.z; ca.w += v.w;
    rowbuf[(wave * 16 + i) * 65 + lane] = (v.x + v.y) + (v.z + v.w);
  }
  colbuf[wave * 64 + lane] = ca;
  __syncthreads();

  if (threadIdx.x < 64) {
    // wave 0: row reduce. thread t sums 64 lane-partials of row t.
    float s = 0.f;
#pragma unroll 8
    for (int l = 0; l < 64; ++l) s += rowbuf[threadIdx.x * 65 + l];
    rowpart[(size_t)blockIdx.x * N + blockIdx.y * 64 + threadIdx.x] = s;
  } else if (threadIdx.x < 128) {
    // wave 1 (concurrent with wave 0): column reduce over this block's 64 rows.
    const int l = threadIdx.x - 64;
    float4 a = colbuf[l], b = colbuf[64 + l], c = colbuf[128 + l],
           d = colbuf[192 + l];
    float4 s = make_float4((a.x + b.x) + (c.x + d.x),
                           (a.y + b.y) + (c.y + d.y),
                           (a.z + b.z) + (c.z + d.z),
                           (a.w + b.w) + (c.w + d.w));
    colpart[(size_t)blockIdx.y * N4 + blockIdx.x * 64 + l] = s;
  }
}

__global__ __launch_bounds__(256) void pass2_kernel(
    const float4* __restrict__ colpart, const float* __restrict__ rowpart,
    float* __restrict__ out) {
  // 32 blocks x 256 threads: 4 threads per f4-column.
  const int jj = threadIdx.x >> 2;       // 0..63: f4-col within block
  const int q = threadIdx.x & 3;         // quarter of the fold
  const int j = blockIdx.x * 64 + jj;    // f4-col index, 0..2047

  float4 c = make_float4(0.f, 0.f, 0.f, 0.f);
#pragma unroll 4
  for (int by = q; by < 128; by += 4) {  // 32 of 128 colpart bands
    float4 v = colpart[(size_t)by * N4 + j];
    c.x += v.x; c.y += v.y; c.z += v.z; c.w += v.w;
  }

  const float4* __restrict__ rowpart4 =
      reinterpret_cast<const float4*>(rowpart);
  float4 r = make_float4(0.f, 0.f, 0.f, 0.f);
#pragma unroll
  for (int bx = q; bx < 32; bx += 4) {   // 8 of 32 rowpart bands
    float4 v = rowpart4[(size_t)bx * N4 + j];
    r.x += v.x; r.y += v.y; r.z += v.z; r.w += v.w;
  }

  // combine the 4 quarter-folds: lanes within a 4-lane group differ only in q.
#pragma unroll
  for (int m = 1; m <= 2; m <<= 1) {
    c.x += __shfl_xor(c.x, m, 64); c.y += __shfl_xor(c.y, m, 64);
    c.z += __shfl_xor(c.z, m, 64); c.w += __shfl_xor(c.w, m, 64);
    r.x += __shfl_xor(r.x, m, 64); r.y += __shfl_xor(r.y, m, 64);
    r.z += __shfl_xor(r.z, m, 64); r.w += __shfl_xor(r.w, m, 64);
  }

  float s = (q == 0) ? (fabsf(r.x - c.x) + fabsf(r.y - c.y)) +
                           (fabsf(r.z - c.z) + fabsf(r.w - c.w))
                     : 0.f;
#pragma unroll
  for (int off = 32; off > 0; off >>= 1) s += __shfl_down(s, off, 64);

  __shared__ float wsum[4];
  if ((threadIdx.x & 63) == 0) wsum[threadIdx.x >> 6] = s;
  __syncthreads();
  if (threadIdx.x == 0)
    atomicAdd(out, (wsum[0] + wsum[1]) + (wsum[2] + wsum[3]));
}

extern "C" void kernel_launch(void* const* d_in, const int* in_sizes, int n_in,
                              void* d_out, int out_size, void* d_ws, size_t ws_size,
                              hipStream_t stream) {
  const float* flow = (const float*)d_in[0];
  float* out = (float*)d_out;
  float4* colpart = (float4*)d_ws;                                   // 4 MB
  float* rowpart = (float*)((char*)d_ws + (size_t)4 * 1024 * 1024);  // 1 MB

  hipMemsetAsync(out, 0, sizeof(float), stream);  // 4 bytes, only init needed

  dim3 grid(N / 256, N / 64);  // (32, 128) = 4096 blocks
  pass1_kernel<<<grid, 256, 0, stream>>>(flow, colpart, rowpart);
  pass2_kernel<<<32, 256, 0, stream>>>(colpart, rowpart, out);
}